// Round 2
// baseline (3201.944 us; speedup 1.0000x reference)
//
#include <hip/hip_runtime.h>

#define NB 512      // batch
#define NK 1152     // input capsules
#define ND 8        // in dim
#define NU 16       // out dim
#define NJ 10       // output capsules
#define EPSQ 1e-7f

// ws layout (in floats)
#define OFF_B  0                       // b_logits [NK][NJ]   (11520)
#define OFF_C  11520                   // c        [NK]       (1152)
#define OFF_V  12672                   // v        [NB][NU]   (8192)
#define OFF_WT 20864                   // WT       [NJ][NK][NU][ND]
#define WT_FLOATS (NJ*NK*NU*ND)        // 1474560
#define WS_FLOATS (OFF_WT + WT_FLOATS) // 1495424 floats = ~6 MB

// ---------------------------------------------------------------------------
// init: zero b_logits, build WT[j][k][u][d] = W[j][k][d][u]
// ---------------------------------------------------------------------------
__global__ __launch_bounds__(256) void caps_init(const float* __restrict__ W,
                                                 float* __restrict__ bl,
                                                 float* __restrict__ WT,
                                                 int use_wt) {
  int idx = blockIdx.x * 256 + threadIdx.x;
  if (idx < NK * NJ) bl[idx] = 0.f;
  if (use_wt && idx < WT_FLOATS) {
    int d = idx & 7;
    int u = (idx >> 3) & 15;
    int k = (idx >> 7) % NK;
    int j = idx / (NK * NU * ND);
    WT[idx] = W[((size_t)(j * NK + k) * ND + d) * NU + u];
  }
}

// ---------------------------------------------------------------------------
// K1: per-k. If ja>=0: agree[k] = sum_{b,u} uhat_ja[b,k,u]*v[b,u];
//     b_logits[k][ja]+=agree. Then c[k] = softmax(b_logits[k])[jc].
// grid 288 x 256; wave kl handles k = blockIdx*4 + kl
// ---------------------------------------------------------------------------
__global__ __launch_bounds__(256) void caps_update(const float* __restrict__ x,
                                                   const float* __restrict__ W,
                                                   const float* __restrict__ v,
                                                   float* __restrict__ bl,
                                                   float* __restrict__ cg,
                                                   int ja, int jc) {
  __shared__ float lds_x[64 * 34];   // 64 b-rows, 32 used floats, pitch 34 (2-way-free banks)
  __shared__ float lds_w[4][128];    // W[ja][k][d][u] per wave's k
  const int t = threadIdx.x;
  const int kl = t >> 6;
  const int lane = t & 63;
  const int k0 = blockIdx.x * 4;
  const int k = k0 + kl;

  float ag = 0.f;
  if (ja >= 0) {
    for (int i = t; i < 512; i += 256) {
      int kk = i >> 7, du = i & 127;
      lds_w[kk][du] = W[(size_t)((ja * NK + k0 + kk) * 128) + du];
    }
    for (int ch = 0; ch < 8; ++ch) {
      const int bbase = ch * 64;
      {  // stage x[bbase..+63][k0..k0+3][0..7] -> LDS (coalesced 128B rows)
        int br = t >> 2, q = t & 3;
        const float2* gp =
            (const float2*)(x + (size_t)(bbase + br) * (NK * ND) + k0 * ND) + q * 4;
        float2* lp = (float2*)(&lds_x[br * 34 + q * 8]);
#pragma unroll
        for (int i2 = 0; i2 < 4; ++i2) lp[i2] = gp[i2];
      }
      __syncthreads();
      const int b = bbase + lane;
      float vv[16];
      const float* vp = v + (size_t)b * NU;
#pragma unroll
      for (int i = 0; i < 16; ++i) vv[i] = vp[i];
      float xd[8];
#pragma unroll
      for (int i = 0; i < 8; ++i) xd[i] = lds_x[lane * 34 + kl * 8 + i];
      float tmp[16];
#pragma unroll
      for (int u = 0; u < 16; ++u) tmp[u] = 0.f;
#pragma unroll
      for (int d = 0; d < 8; ++d) {
        const float xv = xd[d];
#pragma unroll
        for (int u = 0; u < 16; ++u) tmp[u] = fmaf(xv, lds_w[kl][d * 16 + u], tmp[u]);
      }
      float dot = 0.f;
#pragma unroll
      for (int u = 0; u < 16; ++u) dot = fmaf(tmp[u], vv[u], dot);
      ag += dot;
      __syncthreads();
    }
#pragma unroll
    for (int off = 32; off; off >>= 1) ag += __shfl_down(ag, off, 64);
  }

  if (lane == 0) {
    float* row = bl + (size_t)k * NJ;
    if (ja >= 0) row[ja] += ag;
    float r[NJ];
#pragma unroll
    for (int jj = 0; jj < NJ; ++jj) r[jj] = row[jj];
    float mx = r[0];
#pragma unroll
    for (int jj = 1; jj < NJ; ++jj) mx = fmaxf(mx, r[jj]);
    float se = 0.f;
#pragma unroll
    for (int jj = 0; jj < NJ; ++jj) se += __expf(r[jj] - mx);
    cg[k] = __expf(r[jc] - mx) / se;
  }
}

// ---------------------------------------------------------------------------
// K2: per-b. s[b,u] = sum_k c_k * (x[b,k,:]·W[js,k,:,u]); v = squash(s);
//     write v (and out[:,js,:] if wout).
// grid 128 x 256; wave = b = blockIdx*4 + (t>>6); lanes (u = bits2-5, ks = bits0-1)
// ---------------------------------------------------------------------------
__global__ __launch_bounds__(256) void caps_sv(const float* __restrict__ x,
                                               const float* __restrict__ WT,
                                               const float* __restrict__ W,
                                               const float* __restrict__ cg,
                                               float* __restrict__ v,
                                               float* __restrict__ out,
                                               int js, int wout, int use_wt) {
  const int t = threadIdx.x;
  const int b = blockIdx.x * 4 + (t >> 6);
  const int u = (t >> 2) & 15;
  const int ks = t & 3;
  const float* xb = x + (size_t)b * (NK * ND);
  float acc = 0.f;

  if (use_wt) {
    const float* wbase = WT + ((size_t)js * NK * NU + u) * ND;
    for (int kk = 0; kk < NK / 4; ++kk) {
      const int k = kk * 4 + ks;
      const float4* xp = (const float4*)(xb + k * ND);
      const float4 xa = xp[0], xc = xp[1];
      const float4* wp = (const float4*)(wbase + (size_t)k * (NU * ND));
      const float4 wa = wp[0], wb = wp[1];
      const float ck = cg[k];
      float dot = xa.x * wa.x + xa.y * wa.y + xa.z * wa.z + xa.w * wa.w +
                  xc.x * wb.x + xc.y * wb.y + xc.z * wb.z + xc.w * wb.w;
      acc = fmaf(ck, dot, acc);
    }
  } else {
    for (int kk = 0; kk < NK / 4; ++kk) {
      const int k = kk * 4 + ks;
      const float4* xp = (const float4*)(xb + k * ND);
      const float4 xa = xp[0], xc = xp[1];
      const float* wp = W + (size_t)(js * NK + k) * (ND * NU) + u;
      const float ck = cg[k];
      float dot = xa.x * wp[0] + xa.y * wp[16] + xa.z * wp[32] + xa.w * wp[48] +
                  xc.x * wp[64] + xc.y * wp[80] + xc.z * wp[96] + xc.w * wp[112];
      acc = fmaf(ck, dot, acc);
    }
  }

  // reduce over ks (lane bits 0-1): all 4 ks-copies now hold the full s[b][u]
  acc += __shfl_xor(acc, 1, 64);
  acc += __shfl_xor(acc, 2, 64);
  // |s|^2 via butterfly over u bits (lane bits 2-5). ks bits are NOT in the
  // butterfly, so each of the 16 lanes contributes a distinct u exactly once:
  // result = sum_u s[u]^2 exactly (no overcount — the old *0.25 was the R1 bug).
  float sq = acc * acc;
  sq += __shfl_xor(sq, 4, 64);
  sq += __shfl_xor(sq, 8, 64);
  sq += __shfl_xor(sq, 16, 64);
  sq += __shfl_xor(sq, 32, 64);
  const float scale = (sq / (1.f + sq)) / (sqrtf(sq) + EPSQ);
  const float vv = scale * acc;
  if (ks == 0) {
    v[(size_t)b * NU + u] = vv;
    if (wout) out[((size_t)b * NJ + js) * NU + u] = vv;
  }
}

// ---------------------------------------------------------------------------
extern "C" void kernel_launch(void* const* d_in, const int* in_sizes, int n_in,
                              void* d_out, int out_size, void* d_ws, size_t ws_size,
                              hipStream_t stream) {
  (void)in_sizes; (void)n_in; (void)out_size;
  const float* x = (const float*)d_in[0];   // [512][1152][8][1] fp32
  const float* W = (const float*)d_in[1];   // [10][1152][8][16] fp32
  float* out = (float*)d_out;               // [512][10][16][1] fp32
  float* ws = (float*)d_ws;
  float* bl = ws + OFF_B;
  float* cg = ws + OFF_C;
  float* v  = ws + OFF_V;
  float* WT = ws + OFF_WT;
  const int use_wt = (ws_size >= (size_t)WS_FLOATS * 4) ? 1 : 0;
  const int initN = use_wt ? WT_FLOATS : (NK * NJ);

  caps_init<<<(initN + 255) / 256, 256, 0, stream>>>(W, bl, WT, use_wt);
  for (int j = 0; j < NJ; ++j) {
    for (int tt = 0; tt < 3; ++tt) {
      // t==0 folds in the final agree-update of the previous capsule (W[j-1]),
      // then softmaxes column j. Matches reference b_IJ carry-over exactly.
      const int ja = (tt == 0) ? (j - 1) : j;
      caps_update<<<288, 256, 0, stream>>>(x, W, v, bl, cg, ja, j);
      caps_sv<<<128, 256, 0, stream>>>(x, WT, W, cg, v, out, j, (tt == 2) ? 1 : 0, use_wt);
    }
  }
}

// Round 3
// 1749.093 us; speedup vs baseline: 1.8306x; 1.8306x over previous
//
#include <hip/hip_runtime.h>

#define NB 512      // batch
#define NK 1152     // input capsules
#define ND 8        // in dim
#define NU 16       // out dim
#define NJ 10       // output capsules
#define EPSQ 1e-7f
#define KC 18       // split-K chunks for caps_part
#define KCHUNK 64   // k's per chunk (KC*KCHUNK == NK)

// ws layout (in floats)
#define OFF_B  0                        // b_logits [NK][NJ]   (11520)
#define OFF_C  11520                    // c        [NK]       (1152)
#define OFF_V  12672                    // v        [NB][NU]   (8192)
#define OFF_P  20864                    // partial  [KC][NB][NU] (147456)
#define PART_FLOATS (KC*NB*NU)
#define OFF_WT (OFF_P + PART_FLOATS)    // 168320
#define WT_FLOATS (NJ*NK*NU*ND)         // 1474560
#define WS_FLOATS (OFF_WT + WT_FLOATS)  // ~6.6 MB
#define WS_MIN_SPLITK ((OFF_P + PART_FLOATS) * 4)

// ---------------------------------------------------------------------------
// init: zero b_logits, build WT[j][k][u][d] = W[j][k][d][u]
// ---------------------------------------------------------------------------
__global__ __launch_bounds__(256) void caps_init(const float* __restrict__ W,
                                                 float* __restrict__ bl,
                                                 float* __restrict__ WT,
                                                 int use_wt) {
  int idx = blockIdx.x * 256 + threadIdx.x;
  if (idx < NK * NJ) bl[idx] = 0.f;
  if (use_wt && idx < WT_FLOATS) {
    int d = idx & 7;
    int u = (idx >> 3) & 15;
    int k = (idx >> 7) % NK;
    int j = idx / (NK * NU * ND);
    WT[idx] = W[((size_t)(j * NK + k) * ND + d) * NU + u];
  }
}

// ---------------------------------------------------------------------------
// K1: per-k. If ja>=0: agree[k] = sum_{b,u} uhat_ja[b,k,u]*v[b,u];
//     b_logits[k][ja]+=agree. Then c[k] = softmax(b_logits[k])[jc].
// grid 288 x 256; wave kl handles k = blockIdx*4 + kl
// ---------------------------------------------------------------------------
__global__ __launch_bounds__(256) void caps_update(const float* __restrict__ x,
                                                   const float* __restrict__ W,
                                                   const float* __restrict__ v,
                                                   float* __restrict__ bl,
                                                   float* __restrict__ cg,
                                                   int ja, int jc) {
  __shared__ float lds_x[64 * 34];
  __shared__ float lds_w[4][128];
  const int t = threadIdx.x;
  const int kl = t >> 6;
  const int lane = t & 63;
  const int k0 = blockIdx.x * 4;
  const int k = k0 + kl;

  float ag = 0.f;
  if (ja >= 0) {
    for (int i = t; i < 512; i += 256) {
      int kk = i >> 7, du = i & 127;
      lds_w[kk][du] = W[(size_t)((ja * NK + k0 + kk) * 128) + du];
    }
    for (int ch = 0; ch < 8; ++ch) {
      const int bbase = ch * 64;
      {
        int br = t >> 2, q = t & 3;
        const float2* gp =
            (const float2*)(x + (size_t)(bbase + br) * (NK * ND) + k0 * ND) + q * 4;
        float2* lp = (float2*)(&lds_x[br * 34 + q * 8]);
#pragma unroll
        for (int i2 = 0; i2 < 4; ++i2) lp[i2] = gp[i2];
      }
      __syncthreads();
      const int b = bbase + lane;
      float vv[16];
      const float* vp = v + (size_t)b * NU;
#pragma unroll
      for (int i = 0; i < 16; ++i) vv[i] = vp[i];
      float xd[8];
#pragma unroll
      for (int i = 0; i < 8; ++i) xd[i] = lds_x[lane * 34 + kl * 8 + i];
      float tmp[16];
#pragma unroll
      for (int u = 0; u < 16; ++u) tmp[u] = 0.f;
#pragma unroll
      for (int d = 0; d < 8; ++d) {
        const float xv = xd[d];
#pragma unroll
        for (int u = 0; u < 16; ++u) tmp[u] = fmaf(xv, lds_w[kl][d * 16 + u], tmp[u]);
      }
      float dot = 0.f;
#pragma unroll
      for (int u = 0; u < 16; ++u) dot = fmaf(tmp[u], vv[u], dot);
      ag += dot;
      __syncthreads();
    }
#pragma unroll
    for (int off = 32; off; off >>= 1) ag += __shfl_down(ag, off, 64);
  }

  if (lane == 0) {
    float* row = bl + (size_t)k * NJ;
    if (ja >= 0) row[ja] += ag;
    float r[NJ];
#pragma unroll
    for (int jj = 0; jj < NJ; ++jj) r[jj] = row[jj];
    float mx = r[0];
#pragma unroll
    for (int jj = 1; jj < NJ; ++jj) mx = fmaxf(mx, r[jj]);
    float se = 0.f;
#pragma unroll
    for (int jj = 0; jj < NJ; ++jj) se += __expf(r[jj] - mx);
    cg[k] = __expf(r[jc] - mx) / se;
  }
}

// ---------------------------------------------------------------------------
// caps_part: split-K partial of s[b,u] = sum_k c_k*(x[b,k,:]·W[js,k,:,u]).
// grid = KC*128 blocks x 256; block = (kc = bid%KC, bgroup = bid/KC);
// wave = b in group; lane = (u = bits2-5, ks = bits0-1); 16 k-iters/thread.
// writes partial[kc][b][u].
// ---------------------------------------------------------------------------
__global__ __launch_bounds__(256) void caps_part(const float* __restrict__ x,
                                                 const float* __restrict__ WT,
                                                 const float* __restrict__ W,
                                                 const float* __restrict__ cg,
                                                 float* __restrict__ partial,
                                                 int js, int use_wt) {
  const int t = threadIdx.x;
  const int lane = t & 63;
  const int u = lane >> 2;
  const int ks = lane & 3;
  const int bid = blockIdx.x;
  const int kc = bid % KC;
  const int b = (bid / KC) * 4 + (t >> 6);
  const int k0 = kc * KCHUNK;
  const float* xb = x + (size_t)b * (NK * ND) + (size_t)k0 * ND;
  const float* cgc = cg + k0;
  float acc = 0.f;

  if (use_wt) {
    const float* wb = WT + ((size_t)js * NK + k0) * (NU * ND) + u * ND;
#pragma unroll 4
    for (int it = 0; it < KCHUNK / 4; ++it) {
      const int kk = it * 4 + ks;
      const float4* xp = (const float4*)(xb + kk * ND);
      const float4 xa = xp[0], xc = xp[1];
      const float4* wp = (const float4*)(wb + (size_t)kk * (NU * ND));
      const float4 wa = wp[0], wv = wp[1];
      const float ck = cgc[kk];
      float dot = xa.x * wa.x + xa.y * wa.y + xa.z * wa.z + xa.w * wa.w +
                  xc.x * wv.x + xc.y * wv.y + xc.z * wv.z + xc.w * wv.w;
      acc = fmaf(ck, dot, acc);
    }
  } else {
    const float* wb = W + ((size_t)js * NK + k0) * (ND * NU) + u;
#pragma unroll 4
    for (int it = 0; it < KCHUNK / 4; ++it) {
      const int kk = it * 4 + ks;
      const float4* xp = (const float4*)(xb + kk * ND);
      const float4 xa = xp[0], xc = xp[1];
      const float* wp = wb + (size_t)kk * (ND * NU);
      const float ck = cgc[kk];
      float dot = xa.x * wp[0] + xa.y * wp[16] + xa.z * wp[32] + xa.w * wp[48] +
                  xc.x * wp[64] + xc.y * wp[80] + xc.z * wp[96] + xc.w * wp[112];
      acc = fmaf(ck, dot, acc);
    }
  }

  acc += __shfl_xor(acc, 1, 64);
  acc += __shfl_xor(acc, 2, 64);
  if (ks == 0) partial[(size_t)kc * (NB * NU) + (size_t)b * NU + u] = acc;
}

// ---------------------------------------------------------------------------
// caps_fin: s[b,u] = sum_kc partial; v = squash(s); write v (+out if wout).
// grid 32 x 256; lane = (b-sub = bits 4-5, u = bits 0-3); butterfly over u.
// ---------------------------------------------------------------------------
__global__ __launch_bounds__(256) void caps_fin(const float* __restrict__ partial,
                                                float* __restrict__ v,
                                                float* __restrict__ out,
                                                int js, int wout) {
  const int t = threadIdx.x;
  const int b = blockIdx.x * 16 + (t >> 4);
  const int u = t & 15;
  float s = 0.f;
#pragma unroll
  for (int kc = 0; kc < KC; ++kc)
    s += partial[(size_t)kc * (NB * NU) + (size_t)b * NU + u];
  float sq = s * s;
  sq += __shfl_xor(sq, 1, 64);
  sq += __shfl_xor(sq, 2, 64);
  sq += __shfl_xor(sq, 4, 64);
  sq += __shfl_xor(sq, 8, 64);
  const float scale = (sq / (1.f + sq)) / (sqrtf(sq) + EPSQ);
  const float vv = scale * s;
  v[(size_t)b * NU + u] = vv;
  if (wout) out[((size_t)b * NJ + js) * NU + u] = vv;
}

// ---------------------------------------------------------------------------
// Fallback single-kernel s+v (R2 version), used only if ws too small.
// ---------------------------------------------------------------------------
__global__ __launch_bounds__(256) void caps_sv(const float* __restrict__ x,
                                               const float* __restrict__ W,
                                               const float* __restrict__ cg,
                                               float* __restrict__ v,
                                               float* __restrict__ out,
                                               int js, int wout) {
  const int t = threadIdx.x;
  const int b = blockIdx.x * 4 + (t >> 6);
  const int u = (t >> 2) & 15;
  const int ks = t & 3;
  const float* xb = x + (size_t)b * (NK * ND);
  float acc = 0.f;
  for (int kk = 0; kk < NK / 4; ++kk) {
    const int k = kk * 4 + ks;
    const float4* xp = (const float4*)(xb + k * ND);
    const float4 xa = xp[0], xc = xp[1];
    const float* wp = W + (size_t)(js * NK + k) * (ND * NU) + u;
    const float ck = cg[k];
    float dot = xa.x * wp[0] + xa.y * wp[16] + xa.z * wp[32] + xa.w * wp[48] +
                xc.x * wp[64] + xc.y * wp[80] + xc.z * wp[96] + xc.w * wp[112];
    acc = fmaf(ck, dot, acc);
  }
  acc += __shfl_xor(acc, 1, 64);
  acc += __shfl_xor(acc, 2, 64);
  float sq = acc * acc;
  sq += __shfl_xor(sq, 4, 64);
  sq += __shfl_xor(sq, 8, 64);
  sq += __shfl_xor(sq, 16, 64);
  sq += __shfl_xor(sq, 32, 64);
  const float scale = (sq / (1.f + sq)) / (sqrtf(sq) + EPSQ);
  const float vv = scale * acc;
  if (ks == 0) {
    v[(size_t)b * NU + u] = vv;
    if (wout) out[((size_t)b * NJ + js) * NU + u] = vv;
  }
}

// ---------------------------------------------------------------------------
extern "C" void kernel_launch(void* const* d_in, const int* in_sizes, int n_in,
                              void* d_out, int out_size, void* d_ws, size_t ws_size,
                              hipStream_t stream) {
  (void)in_sizes; (void)n_in; (void)out_size;
  const float* x = (const float*)d_in[0];   // [512][1152][8][1] fp32
  const float* W = (const float*)d_in[1];   // [10][1152][8][16] fp32
  float* out = (float*)d_out;               // [512][10][16][1] fp32
  float* ws = (float*)d_ws;
  float* bl = ws + OFF_B;
  float* cg = ws + OFF_C;
  float* v  = ws + OFF_V;
  float* pt = ws + OFF_P;
  float* WT = ws + OFF_WT;
  const int use_wt = (ws_size >= (size_t)WS_FLOATS * 4) ? 1 : 0;
  const int splitk = (ws_size >= (size_t)WS_MIN_SPLITK) ? 1 : 0;
  const int initN = use_wt ? WT_FLOATS : (NK * NJ);

  caps_init<<<(initN + 255) / 256, 256, 0, stream>>>(W, bl, WT, use_wt);
  for (int j = 0; j < NJ; ++j) {
    for (int tt = 0; tt < 3; ++tt) {
      const int ja = (tt == 0) ? (j - 1) : j;
      caps_update<<<288, 256, 0, stream>>>(x, W, v, bl, cg, ja, j);
      if (splitk) {
        caps_part<<<KC * (NB / 4), 256, 0, stream>>>(x, WT, W, cg, pt, j, use_wt);
        caps_fin<<<NB / 16, 256, 0, stream>>>(pt, v, out, j, (tt == 2) ? 1 : 0);
      } else {
        caps_sv<<<NB / 4, 256, 0, stream>>>(x, W, cg, v, out, j, (tt == 2) ? 1 : 0);
      }
    }
  }
}

// Round 4
// 798.343 us; speedup vs baseline: 4.0107x; 2.1909x over previous
//
#include <hip/hip_runtime.h>

#define NB 512      // batch
#define NK 1152     // input capsules
#define ND 8        // in dim
#define NU 16       // out dim
#define NJ 10       // output capsules
#define EPSQ 1e-7f
#define KC 18       // k-chunks of 64
#define BGN 32      // b-groups of 16
#define KT 64       // k per tile
#define BT 16       // b per tile

// ws layout (floats)
#define OFF_B   0                        // b_logits [NK][NJ]     11520
#define OFF_C   11520                    // cg       [NK]         1152
#define OFF_AGP 12672                    // agp      [NK][BGN]    36864
#define OFF_P   (12672 + NK*BGN)         // partial  [KC][NB][NU] 147456
#define OFF_WT  (OFF_P + KC*NB*NU)       // WT       [NJ][NK][NU][ND]
#define WT_FLOATS (NJ*NK*NU*ND)          // 1474560
#define WS_FLOATS (OFF_WT + WT_FLOATS)   // ~6.7 MB

#define XP  516   // part: x LDS pitch per b (512+4: 2-way banks only)
#define WKP 164   // w LDS pitch per k (8 u-pairs * 20 + 4: k-lanes 2-way)
#define XAP 132   // agp: x LDS pitch per k (128+4)

// ---------------------------------------------------------------------------
// init: zero b_logits, build WT[j][k][u][d] = W[j][k][d][u]
// ---------------------------------------------------------------------------
__global__ __launch_bounds__(256) void caps_init(const float* __restrict__ W,
                                                 float* __restrict__ bl,
                                                 float* __restrict__ WT) {
  int idx = blockIdx.x * 256 + threadIdx.x;
  if (idx < NK * NJ) bl[idx] = 0.f;
  if (idx < WT_FLOATS) {
    int d = idx & 7;
    int u = (idx >> 3) & 15;
    int k = (idx >> 7) % NK;
    int j = idx / (NK * NU * ND);
    WT[idx] = W[((size_t)(j * NK + k) * ND + d) * NU + u];
  }
}

// ---------------------------------------------------------------------------
// caps_part: partial s. Block = (kc, bg) tile: 16 b x 64 k. LDS-staged.
// Lanes: bg7..0 x-pairs: lane = ug*8 + bpg; thread computes 2b x 2u over 16 k.
// Writes partial[kc][b][u].
// ---------------------------------------------------------------------------
__global__ __launch_bounds__(256) void caps_part(const float* __restrict__ x,
                                                 const float* __restrict__ WT,
                                                 const float* __restrict__ cg,
                                                 float* __restrict__ partial,
                                                 int js) {
  __shared__ float sx[BT * XP];        // [b][k*8+d], pitch 516
  __shared__ float sw[KT * WKP];       // [k][(u>>1)*20 + (u&1)*8 + d], pitch 164
  __shared__ float sc[KT];
  __shared__ float sred[4 * BT * NU];  // [wave][b][u]
  const int tid = threadIdx.x;
  const int kc = blockIdx.x % KC;
  const int bgi = blockIdx.x / KC;
  const int b0 = bgi * BT;
  const int k0 = kc * KT;

  {  // stage x: 16 rows x 128 float4 (coalesced); row stride 2304 float4
    const float4* gx = (const float4*)(x + (size_t)b0 * (NK * ND) + k0 * ND);
    for (int i = tid; i < BT * 128; i += 256) {
      int b = i >> 7, q = i & 127;
      float4 vx = gx[(size_t)b * 2304 + q];
      *(float4*)&sx[b * XP + q * 4] = vx;
    }
  }
  {  // stage w: 64 rows x 32 float4 (contiguous in WT)
    const float4* gw = (const float4*)(WT + ((size_t)js * NK + k0) * (NU * ND));
    for (int i = tid; i < KT * 32; i += 256) {
      int k = i >> 5, r = i & 31;
      int u = r >> 1, h = r & 1;
      float4 vw = gw[i];
      *(float4*)&sw[k * WKP + (u >> 1) * 20 + (u & 1) * 8 + h * 4] = vw;
    }
  }
  if (tid < KT / 4) *(float4*)&sc[tid * 4] = *(const float4*)(cg + k0 + tid * 4);
  __syncthreads();

  const int w = tid >> 6;
  const int lane = tid & 63;
  const int bpg = lane & 7;   // b-pair group
  const int ug = lane >> 3;   // u-pair group
  const int bb = bpg * 2;
  float a00 = 0.f, a01 = 0.f, a10 = 0.f, a11 = 0.f;
  const float* swp = sw + ug * 20;
#pragma unroll 4
  for (int kk = 0; kk < 16; ++kk) {
    const int kl = w * 16 + kk;
    const float ck = sc[kl];
    const float* xr0 = sx + bb * XP + kl * 8;
    const float4 x0 = *(const float4*)xr0;
    const float4 x0b = *(const float4*)(xr0 + 4);
    const float4 x1 = *(const float4*)(xr0 + XP);
    const float4 x1b = *(const float4*)(xr0 + XP + 4);
    const float* wr = swp + kl * WKP;
    const float4 w0 = *(const float4*)wr;
    const float4 w0b = *(const float4*)(wr + 4);
    const float4 w1 = *(const float4*)(wr + 8);
    const float4 w1b = *(const float4*)(wr + 12);
    float d00 = x0.x * w0.x + x0.y * w0.y + x0.z * w0.z + x0.w * w0.w +
                x0b.x * w0b.x + x0b.y * w0b.y + x0b.z * w0b.z + x0b.w * w0b.w;
    float d01 = x0.x * w1.x + x0.y * w1.y + x0.z * w1.z + x0.w * w1.w +
                x0b.x * w1b.x + x0b.y * w1b.y + x0b.z * w1b.z + x0b.w * w1b.w;
    float d10 = x1.x * w0.x + x1.y * w0.y + x1.z * w0.z + x1.w * w0.w +
                x1b.x * w0b.x + x1b.y * w0b.y + x1b.z * w0b.z + x1b.w * w0b.w;
    float d11 = x1.x * w1.x + x1.y * w1.y + x1.z * w1.z + x1.w * w1.w +
                x1b.x * w1b.x + x1b.y * w1b.y + x1b.z * w1b.z + x1b.w * w1b.w;
    a00 = fmaf(ck, d00, a00);
    a01 = fmaf(ck, d01, a01);
    a10 = fmaf(ck, d10, a10);
    a11 = fmaf(ck, d11, a11);
  }
  // per-wave tile -> LDS
  {
    float2 r0 = {a00, a01}, r1 = {a10, a11};
    *(float2*)&sred[(w * BT + bb) * NU + ug * 2] = r0;
    *(float2*)&sred[(w * BT + bb + 1) * NU + ug * 2] = r1;
  }
  __syncthreads();
  {
    int b = tid >> 4, u = tid & 15;
    float s = sred[(0 * BT + b) * NU + u] + sred[(1 * BT + b) * NU + u] +
              sred[(2 * BT + b) * NU + u] + sred[(3 * BT + b) * NU + u];
    partial[(size_t)kc * (NB * NU) + (size_t)(b0 + b) * NU + u] = s;
  }
}

// ---------------------------------------------------------------------------
// caps_agp: agree partials for column ja. Same tiles as caps_part.
// First recomputes v = squash(sum_kc partial) for its 16 b (in-block),
// optionally writing out[:, ja, :] (kc==0 blocks, t==0 transitions).
// Lanes: kl = lane&15 (k), ugA = lane>>4 (4 u each, w-frag in regs).
// Writes agp[k][bgi].
// ---------------------------------------------------------------------------
__global__ __launch_bounds__(256) void caps_agp(const float* __restrict__ x,
                                                const float* __restrict__ WT,
                                                const float* __restrict__ partial,
                                                float* __restrict__ agp,
                                                float* __restrict__ out,
                                                int ja, int wout) {
  __shared__ float sxA[KT * XAP];  // [k][b*8+d], pitch 132
  __shared__ float sw[KT * WKP];   // same layout as caps_part
  __shared__ float sv[BT * NU];
  const int tid = threadIdx.x;
  const int kc = blockIdx.x % KC;
  const int bgi = blockIdx.x / KC;
  const int b0 = bgi * BT;
  const int k0 = kc * KT;

  {  // stage x transposed: [k][b]
    const float4* gx = (const float4*)(x + (size_t)b0 * (NK * ND) + k0 * ND);
    for (int i = tid; i < BT * 128; i += 256) {
      int b = i >> 7, q = i & 127;
      float4 vx = gx[(size_t)b * 2304 + q];
      *(float4*)&sxA[(q >> 1) * XAP + b * 8 + (q & 1) * 4] = vx;
    }
  }
  {  // stage w
    const float4* gw = (const float4*)(WT + ((size_t)ja * NK + k0) * (NU * ND));
    for (int i = tid; i < KT * 32; i += 256) {
      int k = i >> 5, r = i & 31;
      int u = r >> 1, h = r & 1;
      float4 vw = gw[i];
      *(float4*)&sw[k * WKP + (u >> 1) * 20 + (u & 1) * 8 + h * 4] = vw;
    }
  }
  {  // v = squash(sum of 18 partials) for the 16 b of this tile
    int b = tid >> 4, u = tid & 15;
    const float* pp = partial + (size_t)(b0 + b) * NU + u;
    float s = 0.f;
#pragma unroll
    for (int c = 0; c < KC; ++c) s += pp[(size_t)c * (NB * NU)];
    float sq = s * s;                   // wave = 4 b x 16 u; u = lane low 4 bits
    sq += __shfl_xor(sq, 1, 64);
    sq += __shfl_xor(sq, 2, 64);
    sq += __shfl_xor(sq, 4, 64);
    sq += __shfl_xor(sq, 8, 64);
    const float scale = (sq / (1.f + sq)) / (sqrtf(sq) + EPSQ);
    const float vv = scale * s;
    sv[b * NU + u] = vv;
    if (wout && kc == 0) out[((size_t)(b0 + b) * NJ + ja) * NU + u] = vv;
  }
  __syncthreads();

  const int w = tid >> 6;
  const int lane = tid & 63;
  const int kl = lane & 15;
  const int ugA = lane >> 4;
  const int kloc = w * 16 + kl;
  // hoist w fragment: u = ugA*4 + m, m=0..3 -> 32 floats, 8 float4
  const float* wrb = sw + kloc * WKP + (2 * ugA) * 20;
  const float4 wm0a = *(const float4*)(wrb + 0),  wm0b = *(const float4*)(wrb + 4);
  const float4 wm1a = *(const float4*)(wrb + 8),  wm1b = *(const float4*)(wrb + 12);
  const float4 wm2a = *(const float4*)(wrb + 20), wm2b = *(const float4*)(wrb + 24);
  const float4 wm3a = *(const float4*)(wrb + 28), wm3b = *(const float4*)(wrb + 32);
  float agc = 0.f;
#pragma unroll 4
  for (int b = 0; b < BT; ++b) {
    const float* xr = sxA + kloc * XAP + b * 8;
    const float4 xa = *(const float4*)xr;
    const float4 xb = *(const float4*)(xr + 4);
    const float4 vf = *(const float4*)(sv + b * NU + ugA * 4);
    float d0 = xa.x * wm0a.x + xa.y * wm0a.y + xa.z * wm0a.z + xa.w * wm0a.w +
               xb.x * wm0b.x + xb.y * wm0b.y + xb.z * wm0b.z + xb.w * wm0b.w;
    float d1 = xa.x * wm1a.x + xa.y * wm1a.y + xa.z * wm1a.z + xa.w * wm1a.w +
               xb.x * wm1b.x + xb.y * wm1b.y + xb.z * wm1b.z + xb.w * wm1b.w;
    float d2 = xa.x * wm2a.x + xa.y * wm2a.y + xa.z * wm2a.z + xa.w * wm2a.w +
               xb.x * wm2b.x + xb.y * wm2b.y + xb.z * wm2b.z + xb.w * wm2b.w;
    float d3 = xa.x * wm3a.x + xa.y * wm3a.y + xa.z * wm3a.z + xa.w * wm3a.w +
               xb.x * wm3b.x + xb.y * wm3b.y + xb.z * wm3b.z + xb.w * wm3b.w;
    agc = fmaf(vf.x, d0, agc);
    agc = fmaf(vf.y, d1, agc);
    agc = fmaf(vf.z, d2, agc);
    agc = fmaf(vf.w, d3, agc);
  }
  agc += __shfl_xor(agc, 16, 64);
  agc += __shfl_xor(agc, 32, 64);
  if (ugA == 0) agp[(size_t)(k0 + kloc) * BGN + bgi] = agc;
}

// ---------------------------------------------------------------------------
// caps_soft: per-k: bl[k][ja] += sum_bg agp[k][bg]; cg[k] = softmax(bl[k])[jc]
// ---------------------------------------------------------------------------
__global__ __launch_bounds__(256) void caps_soft(const float* __restrict__ agp,
                                                 float* __restrict__ bl,
                                                 float* __restrict__ cg,
                                                 int ja, int jc) {
  int k = blockIdx.x * 256 + threadIdx.x;
  if (k >= NK) return;
  float* row = bl + (size_t)k * NJ;
  if (ja >= 0) {
    const float4* ap = (const float4*)(agp + (size_t)k * BGN);
    float ag = 0.f;
#pragma unroll
    for (int i = 0; i < BGN / 4; ++i) {
      float4 t4 = ap[i];
      ag += t4.x + t4.y + t4.z + t4.w;
    }
    row[ja] += ag;
  }
  float r[NJ];
#pragma unroll
  for (int jj = 0; jj < NJ; ++jj) r[jj] = row[jj];
  float mx = r[0];
#pragma unroll
  for (int jj = 1; jj < NJ; ++jj) mx = fmaxf(mx, r[jj]);
  float se = 0.f;
#pragma unroll
  for (int jj = 0; jj < NJ; ++jj) se += __expf(r[jj] - mx);
  cg[k] = __expf(r[jc] - mx) / se;
}

// ---------------------------------------------------------------------------
// caps_finout: final v for capsule j=9 -> out[:, 9, :]
// ---------------------------------------------------------------------------
__global__ __launch_bounds__(256) void caps_finout(const float* __restrict__ partial,
                                                   float* __restrict__ out) {
  int g = blockIdx.x * 256 + threadIdx.x;  // 8192
  int b = g >> 4, u = g & 15;
  float s = 0.f;
#pragma unroll
  for (int c = 0; c < KC; ++c) s += partial[(size_t)c * (NB * NU) + (size_t)b * NU + u];
  float sq = s * s;
  sq += __shfl_xor(sq, 1, 64);
  sq += __shfl_xor(sq, 2, 64);
  sq += __shfl_xor(sq, 4, 64);
  sq += __shfl_xor(sq, 8, 64);
  const float scale = (sq / (1.f + sq)) / (sqrtf(sq) + EPSQ);
  out[((size_t)b * NJ + (NJ - 1)) * NU + u] = scale * s;
}

// ---------------------------------------------------------------------------
extern "C" void kernel_launch(void* const* d_in, const int* in_sizes, int n_in,
                              void* d_out, int out_size, void* d_ws, size_t ws_size,
                              hipStream_t stream) {
  (void)in_sizes; (void)n_in; (void)out_size; (void)ws_size;
  const float* x = (const float*)d_in[0];   // [512][1152][8][1] fp32
  const float* W = (const float*)d_in[1];   // [10][1152][8][16] fp32
  float* out = (float*)d_out;               // [512][10][16][1] fp32
  float* ws = (float*)d_ws;                 // harness ws ~268 MB >> 6.7 MB needed
  float* bl  = ws + OFF_B;
  float* cg  = ws + OFF_C;
  float* agp = ws + OFF_AGP;
  float* pt  = ws + OFF_P;
  float* WT  = ws + OFF_WT;

  caps_init<<<(WT_FLOATS + 255) / 256, 256, 0, stream>>>(W, bl, WT);
  for (int j = 0; j < NJ; ++j) {
    for (int t = 0; t < 3; ++t) {
      const int ja = (t == 0) ? (j - 1) : j;   // agree column to fold (R2-verified)
      if (!(j == 0 && t == 0))
        caps_agp<<<KC * BGN, 256, 0, stream>>>(x, WT, pt, agp, out, ja,
                                               (t == 0) ? 1 : 0);
      caps_soft<<<(NK + 255) / 256, 256, 0, stream>>>(
          agp, bl, cg, (j == 0 && t == 0) ? -1 : ja, j);
      caps_part<<<KC * BGN, 256, 0, stream>>>(x, WT, cg, pt, j);
    }
  }
  caps_finout<<<(NB * NU) / 256, 256, 0, stream>>>(pt, out);
}